// Round 4
// baseline (259.937 us; speedup 1.0000x reference)
//
#include <hip/hip_runtime.h>
#include <stdint.h>

#define Nn 8192
#define Dd 256
#define Ss 4096
#define Cc 65

#define TI 64          // i-rows per block (full K in LDS)
#define CHUNK 1024     // j per block (256 per wave)
#define NCHUNK (Nn / CHUNK)  // 8
#define NSUB 4         // j-subtiles of 64 per wave
#define KS 16          // k-steps of 16

#define BIGF 3.0e37f

typedef float f4 __attribute__((ext_vector_type(4)));
typedef float f16v __attribute__((ext_vector_type(16)));
typedef __bf16 bf8 __attribute__((ext_vector_type(8)));

__device__ __forceinline__ float wredsum(float v) {
#pragma unroll
  for (int o = 32; o; o >>= 1) v += __shfl_xor(v, o, 64);
  return v;
}
__device__ __forceinline__ float wredmax(float v) {
#pragma unroll
  for (int o = 32; o; o >>= 1) v = fmaxf(v, __shfl_xor(v, o, 64));
  return v;
}

__device__ __forceinline__ unsigned short f2bf(float f) {
  unsigned int u = __float_as_uint(f);
  u = (u + 0x7fffu + ((u >> 16) & 1u)) >> 16;
  return (unsigned short)u;
}

// ---------------- prep: sqn + bf16 cast ----------------
__global__ __launch_bounds__(256) void prep_kernel(const float* __restrict__ X,
                                                   unsigned short* __restrict__ xb,
                                                   float* __restrict__ sqn) {
  int row = blockIdx.x * 4 + (threadIdx.x >> 6);
  int lane = threadIdx.x & 63;
  f4 v = ((const f4*)(X + (size_t)row * Dd))[lane];
  float ss = v[0] * v[0] + v[1] * v[1] + v[2] * v[2] + v[3] * v[3];
  ss = wredsum(ss);
  if (lane == 0) sqn[row] = ss;
  ushort4 o;
  o.x = f2bf(v[0]); o.y = f2bf(v[1]); o.z = f2bf(v[2]); o.w = f2bf(v[3]);
  ((ushort4*)(xb + (size_t)row * Dd))[lane] = o;
}

// ---------------- main: 32x32x16 MFMA Gram + per-wave independent j-streams ----------------
__device__ __forceinline__ void stage16(const void* g, void* l) {
  __builtin_amdgcn_global_load_lds((__attribute__((address_space(1))) void*)g,
                                   (__attribute__((address_space(3))) void*)l, 16, 0, 0);
}

// B-frag read: slice = ks>>1; data 16B-chunk = (ks&1)*2 + hi; slot = chunk ^ ((row>>1)&3)
#define BREAD(ct, ks)                                                            \
  (*(const bf8*)&ldsB[(ks) >> 1][(((ct) * 32 + l31) * 32) +                      \
                                 (((((ks) & 1) * 2 + hi) ^ ((l31 >> 1) & 3)) * 8)])

__global__ __launch_bounds__(256, 3) void dist_kernel(const unsigned short* __restrict__ xb,
                                                      const float* __restrict__ sqn,
                                                      float* __restrict__ top5ws) {
  // 8 slices of [64 rows x 32 ushorts], XOR-chunk layout (slot t of row p holds
  // data chunk t ^ ((p>>1)&3)); 32 KB total.
  __shared__ unsigned short ldsB[8][TI * 32];

  const int tid = threadIdx.x;
  const int lane = tid & 63;
  const int wv = tid >> 6;
  const int l31 = lane & 31;
  const int hi = lane >> 5;   // which half of the wave
  const int r0 = hi * 4;      // C/D row offset

  const int it = blockIdx.x & 127;
  const int chunk = blockIdx.x >> 7;
  const int ib = it * TI;
  const int jw0 = chunk * CHUNK + wv * 256;  // this wave's private j-stream

  // ---- stage i-tile once (B operand), 64 rows x 256 k ----
  const int pr = lane >> 2;
  const int qd = (lane & 3) ^ ((lane >> 3) & 3);
#pragma unroll
  for (int t = 0; t < 8; ++t) {
    int idx = wv * 8 + t;
    int rg = idx & 3, sl = idx >> 2;
    stage16(xb + (size_t)(ib + rg * 16 + pr) * Dd + sl * 32 + qd * 8,
            &ldsB[sl][rg * 512]);
  }
  __syncthreads();  // only barrier; waves are independent afterwards

  float top[2][5];
#pragma unroll
  for (int a = 0; a < 2; ++a)
#pragma unroll
    for (int b = 0; b < 5; ++b) top[a][b] = BIGF;

  for (int jt = 0; jt < NSUB; ++jt) {
    const int jb = jw0 + jt * 64;

    f16v acc[2][2];
#pragma unroll
    for (int a = 0; a < 2; ++a)
#pragma unroll
      for (int b = 0; b < 2; ++b)
#pragma unroll
        for (int r = 0; r < 16; ++r) acc[a][b][r] = 0.f;

    // A (j-stream) per-lane pointers: row = jb + rt*32 + l31, k-offset hi*8
    const unsigned short* A0 = xb + (size_t)(jb + l31) * Dd + hi * 8;
    const unsigned short* A1 = A0 + 32 * Dd;

    bf8 aC0 = *(const bf8*)A0;
    bf8 aC1 = *(const bf8*)A1;
    bf8 aN0 = *(const bf8*)(A0 + 16);
    bf8 aN1 = *(const bf8*)(A1 + 16);
    bf8 bC0 = BREAD(0, 0);
    bf8 bC1 = BREAD(1, 0);

#pragma unroll
    for (int ks = 0; ks < KS; ++ks) {
      bf8 bN0, bN1, aN20, aN21;
      if (ks + 1 < KS) { bN0 = BREAD(0, ks + 1); bN1 = BREAD(1, ks + 1); }
      if (ks + 2 < KS) {
        aN20 = *(const bf8*)(A0 + (ks + 2) * 16);
        aN21 = *(const bf8*)(A1 + (ks + 2) * 16);
      }
      acc[0][0] = __builtin_amdgcn_mfma_f32_32x32x16_bf16(aC0, bC0, acc[0][0], 0, 0, 0);
      acc[0][1] = __builtin_amdgcn_mfma_f32_32x32x16_bf16(aC0, bC1, acc[0][1], 0, 0, 0);
      acc[1][0] = __builtin_amdgcn_mfma_f32_32x32x16_bf16(aC1, bC0, acc[1][0], 0, 0, 0);
      acc[1][1] = __builtin_amdgcn_mfma_f32_32x32x16_bf16(aC1, bC1, acc[1][1], 0, 0, 0);
      if (ks + 1 < KS) { bC0 = bN0; bC1 = bN1; aC0 = aN0; aC1 = aN1; }
      if (ks + 2 < KS) { aN0 = aN20; aN1 = aN21; }
    }

    // ---- epilogue: t = sqn_j - 2*G (sqn_i is a constant shift per i-row) ----
#pragma unroll
    for (int ct = 0; ct < 2; ++ct) {
      float t[32];
#pragma unroll
      for (int rt = 0; rt < 2; ++rt) {
        f4 sq[4];
#pragma unroll
        for (int g = 0; g < 4; ++g) sq[g] = *(const f4*)&sqn[jb + rt * 32 + 8 * g + r0];
#pragma unroll
        for (int r = 0; r < 16; ++r)
          t[rt * 16 + r] = fmaf(acc[rt][ct][r], -2.0f, sq[r >> 2][r & 3]);
        if (jb + rt * 32 == ib + ct * 32) {  // tile contains the diagonal
#pragma unroll
          for (int r = 0; r < 16; ++r)
            if (8 * (r >> 2) + r0 + (r & 3) == l31) t[rt * 16 + r] = BIGF;
        }
      }
      float m[16];
#pragma unroll
      for (int r = 0; r < 16; ++r) m[r] = fminf(t[r], t[16 + r]);
#pragma unroll
      for (int w = 8; w; w >>= 1)
#pragma unroll
        for (int r = 0; r < w; ++r) m[r] = fminf(m[r], m[r + w]);
      if (m[0] < top[ct][4]) {
#pragma unroll
        for (int kk = 0; kk < 32; ++kk) {
          float x = t[kk];
          if (x < top[ct][4]) {
#pragma unroll
            for (int s = 0; s < 4; ++s) {
              float lo = fminf(top[ct][s], x);
              x = fmaxf(top[ct][s], x);
              top[ct][s] = lo;
            }
            top[ct][4] = x;
          }
        }
      }
    }
  }

  // merge the two lanes (l, l^32) that share each i-column, then write
  const int list = chunk * 4 + wv;  // 32 lists/row, 16 per half
#pragma unroll
  for (int ct = 0; ct < 2; ++ct) {
    float a0 = top[ct][0], a1 = top[ct][1], a2 = top[ct][2], a3 = top[ct][3], a4 = top[ct][4];
    float b0 = __shfl_xor(a0, 32, 64);
    float b1 = __shfl_xor(a1, 32, 64);
    float b2 = __shfl_xor(a2, 32, 64);
    float b3 = __shfl_xor(a3, 32, 64);
    float b4 = __shfl_xor(a4, 32, 64);
    float c0 = fminf(a0, b0);
    float c1 = fminf(fminf(a1, b1), fmaxf(a0, b0));
    float c2 = fminf(fminf(a2, b2), fminf(fmaxf(a1, b0), fmaxf(a0, b1)));
    float c3 = fminf(fminf(a3, b3), fminf(fmaxf(a2, b0), fminf(fmaxf(a1, b1), fmaxf(a0, b2))));
    float c4 = fminf(fminf(a4, b4),
                     fminf(fmaxf(a3, b0),
                           fminf(fmaxf(a2, b1), fminf(fmaxf(a1, b2), fmaxf(a0, b3)))));
    if (hi == 0) {
      int i = ib + ct * 32 + l31;
      top5ws[(size_t)(list * 5 + 0) * Nn + i] = c0;
      top5ws[(size_t)(list * 5 + 1) * Nn + i] = c1;
      top5ws[(size_t)(list * 5 + 2) * Nn + i] = c2;
      top5ws[(size_t)(list * 5 + 3) * Nn + i] = c3;
      top5ws[(size_t)(list * 5 + 4) * Nn + i] = c4;
    }
  }
}

// ---------------- merge: safe even if o aliases a ----------------
__device__ __forceinline__ void merge5(const float* a, const float* b, float* o) {
  float t0 = fminf(a[0], b[0]);
  float t1 = fminf(fminf(a[1], b[1]), fmaxf(a[0], b[0]));
  float t2 = fminf(fminf(a[2], b[2]), fminf(fmaxf(a[1], b[0]), fmaxf(a[0], b[1])));
  float t3 = fminf(fminf(a[3], b[3]), fminf(fmaxf(a[2], b[0]), fminf(fmaxf(a[1], b[1]), fmaxf(a[0], b[2]))));
  float t4 = fminf(fminf(a[4], b[4]),
                   fminf(fmaxf(a[3], b[0]),
                         fminf(fmaxf(a[2], b[1]), fminf(fmaxf(a[1], b[2]), fmaxf(a[0], b[3])))));
  o[0] = t0; o[1] = t1; o[2] = t2; o[3] = t3; o[4] = t4;
}

// ---------------- fused tail: loss rows (blocks 0..2047) + reg rows (2048..2079) ----------------
__global__ __launch_bounds__(256) void tail_kernel(const float* __restrict__ logit,
                                                   const int* __restrict__ y,
                                                   const float* __restrict__ top5ws,
                                                   const float* __restrict__ sqn,
                                                   float* __restrict__ out) {
  __shared__ float red[256];
  const int bx = blockIdx.x;
  if (bx < 2048) {
    int row = bx * 4 + (threadIdx.x >> 6);
    int lane = threadIdx.x & 63;
    const float* xr = logit + (size_t)row * Cc;
    float x1 = xr[lane];
    float x2 = (lane == 0) ? xr[64] : -BIGF;
    float mx = wredmax(fmaxf(x1, x2));
    float e1 = expf(x1 - mx);
    float e2 = (lane == 0) ? expf(x2 - mx) : 0.f;
    float Z = wredsum(e1 + e2);
    float res;
    if (row < Ss) {
      int yy = y[row];
      float pick = (lane == yy ? x1 : 0.f) + ((lane == 0 && yy == 64) ? x2 : 0.f);
      float xy = wredsum(pick);
      res = -(xy - mx - logf(Z));
    } else {
      float p1 = e1 / Z;
      float t1 = -p1 * log2f(fmaxf(p1, 1e-8f));
      if (lane == 0) {
        float p2 = e2 / Z;
        t1 += -p2 * log2f(fmaxf(p2, 1e-8f));
      }
      res = wredsum(t1);
    }
    __shared__ float a4[4];
    if (lane == 0) a4[threadIdx.x >> 6] = res;
    __syncthreads();
    if (threadIdx.x == 0) {
      float s = (a4[0] + a4[1] + a4[2] + a4[3]) * (1.0f / 4096.0f);
      atomicAdd(&out[bx < 1024 ? 0 : 1], s);
    }
  } else {
    // one row per thread; merge 16 sorted-5 lists per half
    int i = (bx - 2048) * 256 + threadIdx.x;
    float mm[2][5];
#pragma unroll
    for (int h = 0; h < 2; ++h) {
      float run[5];
#pragma unroll 4
      for (int k = 0; k < 16; ++k) {
        float lv[5];
#pragma unroll
        for (int s = 0; s < 5; ++s) lv[s] = top5ws[(size_t)((h * 16 + k) * 5 + s) * Nn + i];
        if (k == 0) {
#pragma unroll
          for (int s = 0; s < 5; ++s) run[s] = lv[s];
        } else {
          merge5(run, lv, run);
        }
      }
#pragma unroll
      for (int s = 0; s < 5; ++s) mm[h][s] = run[s];
    }
    bool srcRow = (i < Ss);
    int hin = srcRow ? 0 : 1, hout = srcRow ? 1 : 0;
    float A0 = mm[hin][0];  // intra min (diag excluded)
    float A3 = mm[hin][3];  // intra: 4th non-diag == ref's 5th incl diag-0
    float B0 = mm[hout][0];
    float B4 = mm[hout][4];
    float sq = sqn[i];
    float dmin_a = sqrtf(fmaxf(A0 + sq, 0.f));
    float kth_a = sqrtf(fmaxf(A3 + sq, 0.f));
    float dmin_b = sqrtf(fmaxf(B0 + sq, 0.f));
    float kth_b = sqrtf(fmaxf(B4 + sq, 0.f));
    float sa = expf(-dmin_a / (2.f * (kth_a + 1e-8f)));
    float sb = expf(-dmin_b / (2.f * (kth_b + 1e-8f)));
    float v = fabsf(sa - sb);
    red[threadIdx.x] = v;
    __syncthreads();
#pragma unroll
    for (int s = 128; s; s >>= 1) {
      if (threadIdx.x < s) red[threadIdx.x] += red[threadIdx.x + s];
      __syncthreads();
    }
    if (threadIdx.x == 0) atomicAdd(&out[2], red[0] * (1.0f / 4096.0f));
  }
}

extern "C" void kernel_launch(void* const* d_in, const int* in_sizes, int n_in,
                              void* d_out, int out_size, void* d_ws, size_t ws_size,
                              hipStream_t stream) {
  (void)in_sizes; (void)n_in; (void)ws_size;
  const float* X = (const float*)d_in[0];
  const float* logit = (const float*)d_in[1];
  const int* y = (const int*)d_in[2];
  char* ws = (char*)d_ws;

  unsigned short* xb = (unsigned short*)ws;               // 4 MB bf16 features
  float* sqn = (float*)(ws + (4u << 20));                 // 32 KB row norms
  float* top5 = (float*)(ws + (4u << 20) + (64u << 10));  // 5.24 MB top-5 slot planes

  hipMemsetAsync(d_out, 0, (size_t)out_size * 4, stream);
  hipLaunchKernelGGL(prep_kernel, dim3(2048), dim3(256), 0, stream, X, xb, sqn);
  hipLaunchKernelGGL(dist_kernel, dim3((Nn / TI) * NCHUNK), dim3(256), 0, stream, xb, sqn, top5);
  hipLaunchKernelGGL(tail_kernel, dim3(2048 + 32), dim3(256), 0, stream, logit, y, top5, sqn,
                     (float*)d_out);
}

// Round 5
// 171.680 us; speedup vs baseline: 1.5141x; 1.5141x over previous
//
#include <hip/hip_runtime.h>
#include <stdint.h>

#define Nn 8192
#define Dd 256
#define Ss 4096
#define Cc 65

#define TI 64            // i-rows per block (stationary in LDS, frag-major)
#define CHUNK 1024       // j per block; 256 per wave (private stream)
#define NCHUNK (Nn / CHUNK)  // 8

#define BIGF 3.0e37f

typedef float f4 __attribute__((ext_vector_type(4)));
typedef __bf16 bf8 __attribute__((ext_vector_type(8)));

__device__ __forceinline__ float wredsum(float v) {
#pragma unroll
  for (int o = 32; o; o >>= 1) v += __shfl_xor(v, o, 64);
  return v;
}
__device__ __forceinline__ float wredmax(float v) {
#pragma unroll
  for (int o = 32; o; o >>= 1) v = fmaxf(v, __shfl_xor(v, o, 64));
  return v;
}

__device__ __forceinline__ unsigned short f2bf(float f) {
  unsigned int u = __float_as_uint(f);
  u = (u + 0x7fffu + ((u >> 16) & 1u)) >> 16;
  return (unsigned short)u;
}

// ---------------- prep: sqn + bf16 cast into FRAG-MAJOR layout ----------------
// xb2 layout: block (rb = row/16, kc = k/32) is 1 KB: 64 lanes x 16 B, where
// lane = (row&15) + 16*((k&31)>>3), bytes (k&7)*2.  An MFMA A/B-fragment for
// (rb, kc) is then exactly lanes 0..63 consecutive -> one coalesced dwordx4.
__global__ __launch_bounds__(256) void prep_kernel(const float* __restrict__ X,
                                                   unsigned short* __restrict__ xb2,
                                                   float* __restrict__ sqn) {
  int row = blockIdx.x * 4 + (threadIdx.x >> 6);
  int l = threadIdx.x & 63;
  f4 v = ((const f4*)(X + (size_t)row * Dd))[l];  // k = 4l .. 4l+3
  float ss = v[0] * v[0] + v[1] * v[1] + v[2] * v[2] + v[3] * v[3];
  ss = wredsum(ss);
  if (l == 0) sqn[row] = ss;
  ushort4 o;
  o.x = f2bf(v[0]); o.y = f2bf(v[1]); o.z = f2bf(v[2]); o.w = f2bf(v[3]);
  int rb = row >> 4, m = row & 15;
  int kc = l >> 3;
  int lane2 = m + 16 * ((l >> 1) & 3);
  ((ushort4*)xb2)[((size_t)(rb * 8 + kc) * 64 + lane2) * 2 + (l & 1)] = o;
}

// ---------------- main: barrier-free K-loop, A from global, B in LDS ----------------
__device__ __forceinline__ void stage16(const void* g, void* l) {
  __builtin_amdgcn_global_load_lds((__attribute__((address_space(1))) void*)g,
                                   (__attribute__((address_space(3))) void*)l, 16, 0, 0);
}

__global__ __launch_bounds__(256) void dist_kernel(const unsigned short* __restrict__ xb2,
                                                   const float* __restrict__ sqn,
                                                   float* __restrict__ top5ws) {
  __shared__ unsigned short ldsB[TI * Dd];  // 32 KB, verbatim frag-major blocks

  const int tid = threadIdx.x;
  const int lane = tid & 63;
  const int wv = tid >> 6;
  const int q = lane >> 4, c = lane & 15;
  const int it = blockIdx.x & 127;
  const int chunk = blockIdx.x >> 7;
  const int ib = it * TI;
  const int jw0 = chunk * CHUNK + wv * 256;  // this wave's private j-stream
  const int lane8 = lane * 8;

  // ---- stage i-tile once: wave wv stages row-block wv, all 8 k-chunks ----
  {
    const unsigned short* g0 = xb2 + ((size_t)((ib >> 4) + wv) * 8) * 512 + lane8;
#pragma unroll
    for (int t = 0; t < 8; ++t)
      stage16(g0 + t * 512, &ldsB[(wv * 8 + t) * 512]);
  }
  __syncthreads();  // only barrier in the kernel

  float top[4][5];
#pragma unroll
  for (int a = 0; a < 4; ++a)
#pragma unroll
    for (int b = 0; b < 5; ++b) top[a][b] = BIGF;

  const int jb16_0 = jw0 >> 4;
  bf8 aP[3][4], bP[2][4];

#define ALOAD(slot, jt2, ks2)                                                       \
  do {                                                                              \
    const unsigned short* _g =                                                      \
        xb2 + ((size_t)(jb16_0 + (jt2) * 4) * 8 + (ks2)) * 512 + lane8;             \
    aP[slot][0] = *(const bf8*)_g;                                                  \
    aP[slot][1] = *(const bf8*)(_g + 4096);                                         \
    aP[slot][2] = *(const bf8*)(_g + 8192);                                         \
    aP[slot][3] = *(const bf8*)(_g + 12288);                                        \
  } while (0)

#define BREAD(ph, ks2)                                                              \
  do {                                                                              \
    bP[ph][0] = *(const bf8*)&ldsB[((0 * 8 + (ks2)) * 64 + lane) * 8];              \
    bP[ph][1] = *(const bf8*)&ldsB[((1 * 8 + (ks2)) * 64 + lane) * 8];              \
    bP[ph][2] = *(const bf8*)&ldsB[((2 * 8 + (ks2)) * 64 + lane) * 8];              \
    bP[ph][3] = *(const bf8*)&ldsB[((3 * 8 + (ks2)) * 64 + lane) * 8];              \
  } while (0)

  // prime the A pipeline (steps 0 and 1)
  ALOAD(0, 0, 0);
  ALOAD(1, 0, 1);
  BREAD(0, 0);

#pragma unroll
  for (int jt = 0; jt < 4; ++jt) {
    const int jb = jw0 + jt * 64;

    f4 acc[4][4];
    f4 z = {0.f, 0.f, 0.f, 0.f};
#pragma unroll
    for (int a = 0; a < 4; ++a)
#pragma unroll
      for (int b2 = 0; b2 < 4; ++b2) acc[a][b2] = z;

#pragma unroll
    for (int ks = 0; ks < 8; ++ks) {
      const int st = jt * 8 + ks;
      // prefetch B for next step (B-frags are jt-invariant; re-read per jt)
      if (st + 1 < 32) BREAD((ks + 1) & 1, (ks + 1) & 7);
      // prefetch A two steps ahead
      if (st + 2 < 32) ALOAD((st + 2) % 3, (st + 2) >> 3, (st + 2) & 7);
      const int s3 = st % 3, ph = ks & 1;
#pragma unroll
      for (int rt = 0; rt < 4; ++rt)
#pragma unroll
        for (int ct = 0; ct < 4; ++ct)
          acc[rt][ct] =
              __builtin_amdgcn_mfma_f32_16x16x32_bf16(aP[s3][rt], bP[ph][ct], acc[rt][ct], 0, 0, 0);
    }

    // ---- epilogue: t = sqn_j - 2*G  (sqn_i is a constant shift per i-row) ----
    f4 sq4[4];
#pragma unroll
    for (int rt = 0; rt < 4; ++rt) sq4[rt] = *(const f4*)&sqn[jb + rt * 16 + q * 4];
    const bool mayDiag = (jb == ib);
#pragma unroll
    for (int ct = 0; ct < 4; ++ct) {
      float t[16];
#pragma unroll
      for (int rt = 0; rt < 4; ++rt)
#pragma unroll
        for (int r = 0; r < 4; ++r)
          t[rt * 4 + r] = fmaf(acc[rt][ct][r], -2.0f, sq4[rt][r]);
      if (mayDiag && ((c >> 2) == q)) t[ct * 4 + (c & 3)] = BIGF;  // mask j==i
      float tm = fminf(fminf(fminf(fminf(t[0], t[1]), fminf(t[2], t[3])),
                             fminf(fminf(t[4], t[5]), fminf(t[6], t[7]))),
                       fminf(fminf(fminf(t[8], t[9]), fminf(t[10], t[11])),
                             fminf(fminf(t[12], t[13]), fminf(t[14], t[15]))));
      if (tm < top[ct][4]) {
#pragma unroll
        for (int kk = 0; kk < 16; ++kk) {
          float x = t[kk];
          if (x < top[ct][4]) {
#pragma unroll
            for (int s = 0; s < 4; ++s) {
              float lo = fminf(top[ct][s], x);
              x = fmaxf(top[ct][s], x);
              top[ct][s] = lo;
            }
            top[ct][4] = x;
          }
        }
      }
    }
  }
#undef ALOAD
#undef BREAD

  // cross-quad merge of sorted-5 lists, then coalesced slot-plane writes
  const int list = chunk * 4 + wv;  // 32 lists/row, 16 per half
#pragma unroll
  for (int ct = 0; ct < 4; ++ct) {
    float a0 = top[ct][0], a1 = top[ct][1], a2 = top[ct][2], a3 = top[ct][3], a4 = top[ct][4];
#pragma unroll
    for (int off = 16; off <= 32; off <<= 1) {
      float b0 = __shfl_xor(a0, off, 64);
      float b1 = __shfl_xor(a1, off, 64);
      float b2 = __shfl_xor(a2, off, 64);
      float b3 = __shfl_xor(a3, off, 64);
      float b4 = __shfl_xor(a4, off, 64);
      float c0 = fminf(a0, b0);
      float c1 = fminf(fminf(a1, b1), fmaxf(a0, b0));
      float c2 = fminf(fminf(a2, b2), fminf(fmaxf(a1, b0), fmaxf(a0, b1)));
      float c3 = fminf(fminf(a3, b3), fminf(fmaxf(a2, b0), fminf(fmaxf(a1, b1), fmaxf(a0, b2))));
      float c4 = fminf(fminf(a4, b4),
                       fminf(fmaxf(a3, b0),
                             fminf(fmaxf(a2, b1), fminf(fmaxf(a1, b2), fmaxf(a0, b3)))));
      a0 = c0; a1 = c1; a2 = c2; a3 = c3; a4 = c4;
    }
    if (q == 0) {
      int i = ib + ct * 16 + c;
      top5ws[(size_t)(list * 5 + 0) * Nn + i] = a0;
      top5ws[(size_t)(list * 5 + 1) * Nn + i] = a1;
      top5ws[(size_t)(list * 5 + 2) * Nn + i] = a2;
      top5ws[(size_t)(list * 5 + 3) * Nn + i] = a3;
      top5ws[(size_t)(list * 5 + 4) * Nn + i] = a4;
    }
  }
}

// ---------------- merge: safe even if o aliases a ----------------
__device__ __forceinline__ void merge5(const float* a, const float* b, float* o) {
  float t0 = fminf(a[0], b[0]);
  float t1 = fminf(fminf(a[1], b[1]), fmaxf(a[0], b[0]));
  float t2 = fminf(fminf(a[2], b[2]), fminf(fmaxf(a[1], b[0]), fmaxf(a[0], b[1])));
  float t3 = fminf(fminf(a[3], b[3]), fminf(fmaxf(a[2], b[0]), fminf(fmaxf(a[1], b[1]), fmaxf(a[0], b[2]))));
  float t4 = fminf(fminf(a[4], b[4]),
                   fminf(fmaxf(a[3], b[0]),
                         fminf(fmaxf(a[2], b[1]), fminf(fmaxf(a[1], b[2]), fmaxf(a[0], b[3])))));
  o[0] = t0; o[1] = t1; o[2] = t2; o[3] = t3; o[4] = t4;
}

// ---------------- fused tail: loss rows (blocks 0..2047) + reg rows (2048..2079) ----------------
__global__ __launch_bounds__(256) void tail_kernel(const float* __restrict__ logit,
                                                   const int* __restrict__ y,
                                                   const float* __restrict__ top5ws,
                                                   const float* __restrict__ sqn,
                                                   float* __restrict__ out) {
  __shared__ float red[256];
  const int bx = blockIdx.x;
  if (bx < 2048) {
    int row = bx * 4 + (threadIdx.x >> 6);
    int lane = threadIdx.x & 63;
    const float* xr = logit + (size_t)row * Cc;
    float x1 = xr[lane];
    float x2 = (lane == 0) ? xr[64] : -BIGF;
    float mx = wredmax(fmaxf(x1, x2));
    float e1 = expf(x1 - mx);
    float e2 = (lane == 0) ? expf(x2 - mx) : 0.f;
    float Z = wredsum(e1 + e2);
    float res;
    if (row < Ss) {
      int yy = y[row];
      float pick = (lane == yy ? x1 : 0.f) + ((lane == 0 && yy == 64) ? x2 : 0.f);
      float xy = wredsum(pick);
      res = -(xy - mx - logf(Z));
    } else {
      float p1 = e1 / Z;
      float t1 = -p1 * log2f(fmaxf(p1, 1e-8f));
      if (lane == 0) {
        float p2 = e2 / Z;
        t1 += -p2 * log2f(fmaxf(p2, 1e-8f));
      }
      res = wredsum(t1);
    }
    __shared__ float a4[4];
    if (lane == 0) a4[threadIdx.x >> 6] = res;
    __syncthreads();
    if (threadIdx.x == 0) {
      float s = (a4[0] + a4[1] + a4[2] + a4[3]) * (1.0f / 4096.0f);
      atomicAdd(&out[bx < 1024 ? 0 : 1], s);
    }
  } else {
    // one row per thread; merge 16 sorted-5 lists per half
    int i = (bx - 2048) * 256 + threadIdx.x;
    float mm[2][5];
#pragma unroll
    for (int h = 0; h < 2; ++h) {
      float run[5];
#pragma unroll 4
      for (int k = 0; k < 16; ++k) {
        float lv[5];
#pragma unroll
        for (int s = 0; s < 5; ++s) lv[s] = top5ws[(size_t)((h * 16 + k) * 5 + s) * Nn + i];
        if (k == 0) {
#pragma unroll
          for (int s = 0; s < 5; ++s) run[s] = lv[s];
        } else {
          merge5(run, lv, run);
        }
      }
#pragma unroll
      for (int s = 0; s < 5; ++s) mm[h][s] = run[s];
    }
    bool srcRow = (i < Ss);
    int hin = srcRow ? 0 : 1, hout = srcRow ? 1 : 0;
    float A0 = mm[hin][0];  // intra min (diag excluded)
    float A3 = mm[hin][3];  // intra: 4th non-diag == ref's 5th incl diag-0
    float B0 = mm[hout][0];
    float B4 = mm[hout][4];
    float sq = sqn[i];
    float dmin_a = sqrtf(fmaxf(A0 + sq, 0.f));
    float kth_a = sqrtf(fmaxf(A3 + sq, 0.f));
    float dmin_b = sqrtf(fmaxf(B0 + sq, 0.f));
    float kth_b = sqrtf(fmaxf(B4 + sq, 0.f));
    float sa = expf(-dmin_a / (2.f * (kth_a + 1e-8f)));
    float sb = expf(-dmin_b / (2.f * (kth_b + 1e-8f)));
    float v = fabsf(sa - sb);
    red[threadIdx.x] = v;
    __syncthreads();
#pragma unroll
    for (int s = 128; s; s >>= 1) {
      if (threadIdx.x < s) red[threadIdx.x] += red[threadIdx.x + s];
      __syncthreads();
    }
    if (threadIdx.x == 0) atomicAdd(&out[2], red[0] * (1.0f / 4096.0f));
  }
}

extern "C" void kernel_launch(void* const* d_in, const int* in_sizes, int n_in,
                              void* d_out, int out_size, void* d_ws, size_t ws_size,
                              hipStream_t stream) {
  (void)in_sizes; (void)n_in; (void)ws_size;
  const float* X = (const float*)d_in[0];
  const float* logit = (const float*)d_in[1];
  const int* y = (const int*)d_in[2];
  char* ws = (char*)d_ws;

  unsigned short* xb2 = (unsigned short*)ws;              // 4 MB bf16 frag-major
  float* sqn = (float*)(ws + (4u << 20));                 // 32 KB row norms
  float* top5 = (float*)(ws + (4u << 20) + (64u << 10));  // 5.24 MB top-5 slot planes

  hipMemsetAsync(d_out, 0, (size_t)out_size * 4, stream);
  hipLaunchKernelGGL(prep_kernel, dim3(2048), dim3(256), 0, stream, X, xb2, sqn);
  hipLaunchKernelGGL(dist_kernel, dim3((Nn / TI) * NCHUNK), dim3(256), 0, stream, xb2, sqn, top5);
  hipLaunchKernelGGL(tail_kernel, dim3(2048 + 32), dim3(256), 0, stream, logit, y, top5, sqn,
                     (float*)d_out);
}